// Round 11
// baseline (5522.450 us; speedup 1.0000x reference)
//
#include <hip/hip_runtime.h>

#define VOCABN 401
#define EN 256
#define HN 768
#define H3N 2304
#define ON 3
#define BN 64
#define TN 1024

// 16 replicas x 16 WGs; WG = 768 threads: 48 j's x 16 k-slices; 4 staged batches
#define NREP 16
#define WGPR 16
#define BPR  4
#define JPW  48
#define NTH  768

typedef _Float16 f16x2 __attribute__((ext_vector_type(2)));
typedef _Float16 f16x8 __attribute__((ext_vector_type(8)));
typedef unsigned long long u64;
union F16x8 { f16x8 v; f16x2 p[4]; };

__device__ __forceinline__ float fdot2(f16x2 a, f16x2 b, float c) {
#if __has_builtin(__builtin_amdgcn_fdot2)
    return __builtin_amdgcn_fdot2(a, b, c, false);
#else
    return c + (float)a[0] * (float)b[0] + (float)a[1] * (float)b[1];
#endif
}

// sum across each aligned 16-lane group; pure-VALU DPP butterfly.
__device__ __forceinline__ float hexsum(float x) {
    int v = __builtin_bit_cast(int, x);
    x += __builtin_bit_cast(float, __builtin_amdgcn_update_dpp(0, v, 0xB1, 0xF, 0xF, true));
    v = __builtin_bit_cast(int, x);
    x += __builtin_bit_cast(float, __builtin_amdgcn_update_dpp(0, v, 0x4E, 0xF, 0xF, true));
    v = __builtin_bit_cast(int, x);
    x += __builtin_bit_cast(float, __builtin_amdgcn_update_dpp(0, v, 0x141, 0xF, 0xF, true));
    v = __builtin_bit_cast(int, x);
    x += __builtin_bit_cast(float, __builtin_amdgcn_update_dpp(0, v, 0x140, 0xF, 0xF, true));
    return x;
}

// ---------------- K1: gtab[v][g] = dot(embed[v], W_ih[g]) + b_ih[g]  (w-stationary)
__global__ __launch_bounds__(256)
void k_build_gtab(const float* __restrict__ embed, const float* __restrict__ wih,
                  const float* __restrict__ bih, float* __restrict__ gtab) {
    const int g  = blockIdx.x * 64 + (threadIdx.x >> 2);
    const int ql = threadIdx.x & 3;
    const int v0 = blockIdx.y * 26;
    const int v1 = min(VOCABN, v0 + 26);
    float4 w[16];
    const float4* s4 = (const float4*)(wih + (size_t)g * EN + ql * 64);
#pragma unroll
    for (int i = 0; i < 16; ++i) w[i] = s4[i];
    const float bias = bih[g];
    for (int v = v0; v < v1; ++v) {
        const float4* e4 = (const float4*)(embed + (size_t)v * EN + ql * 64);
        float acc = 0.f;
#pragma unroll
        for (int i = 0; i < 16; ++i) {
            float4 e = e4[i];
            acc += w[i].x * e.x + w[i].y * e.y + w[i].z * e.z + w[i].w * e.w;
        }
        acc += __shfl_xor(acc, 1, 64);
        acc += __shfl_xor(acc, 2, 64);
        if (ql == 0) gtab[(size_t)v * H3N + g] = acc + bias;
    }
}

// ---------------- K2: persistent-weight recurrence; batch-staggered pipeline,
// gate-thread specialization, depth-2 poll ring.
// h word (u32): [31:16]=step tag, [15:0]=f16 bits; u64 = j-pair. memset-0 == t=0.
// Per stage b: verify+deposit(b) | bar | issue poll(b+2), dot(b), sums->LDS | bar |
// gate threads (tid/48==b): gates, store tagged pair, x-prefetch(t+1).
// Anti-overwrite induction as r9/r10 (verify of (t,b) proves all peers' (t-1,b)
// reads completed -> storing (t+1,b) over (t-1,b) is safe). Agent-scope relaxed.
__global__ __launch_bounds__(NTH, 1)
void k_rnn(const int* __restrict__ tokens, const float* __restrict__ whh,
           const float* __restrict__ gtab, const float* __restrict__ bhh,
           unsigned* __restrict__ hbuf, float* __restrict__ hout) {
    const int R   = blockIdx.x & (NREP - 1);
    const int wg  = blockIdx.x >> 4;
    const int tid = threadIdx.x;
    const int jl  = tid >> 4;                  // 0..47
    const int q   = tid & 15;                  // k-slice
    const int j   = wg * JPW + jl;

    __shared__ __align__(16) _Float16 hlds[BPR * 16 * 56];  // [b][q][48+8pad] = 7168 B
    __shared__ float s_s[3][BPR][JPW];                      // gate sums, 2304 B

    // ---- one-time: weight slice -> 18 statically-indexed f16x8 (72 VGPRs)
    F16x8 w[3][6];
#pragma unroll
    for (int g = 0; g < 3; ++g) {
        const float4* s4 = (const float4*)(whh + (size_t)(g * HN + j) * HN + q * 48);
#pragma unroll
        for (int c = 0; c < 6; ++c) {
            float4 a = s4[2 * c], b4 = s4[2 * c + 1];
            F16x8 t;
            t.v[0] = (_Float16)a.x;  t.v[1] = (_Float16)a.y;
            t.v[2] = (_Float16)a.z;  t.v[3] = (_Float16)a.w;
            t.v[4] = (_Float16)b4.x; t.v[5] = (_Float16)b4.y;
            t.v[6] = (_Float16)b4.z; t.v[7] = (_Float16)b4.w;
            w[g][c] = t;
        }
    }

    u64* hb2 = (u64*)hbuf + (size_t)R * (2 * BPR * 384);
    // poller deposit ptr: u64 word tid covers k-global 2*tid of its batch tile
    unsigned short* dep = (unsigned short*)hlds + (tid / 24) * 56 + (tid % 24) * 2;

    // gate-thread persistent state (tid<192): owns (bown = tid/48, jlown = tid%48)
    const int bown  = tid / 48;
    const int jlown = tid - bown * 48;
    const int jown  = wg * JPW + jlown;
    float hprev = 0.f, xr = 0.f, xz = 0.f, xn = 0.f, bhr = 0.f, bhz = 0.f, bhn = 0.f;
    if (tid < 192) {
        bhr = bhh[jown]; bhz = bhh[HN + jown]; bhn = bhh[2 * HN + jown];
        const int tok = tokens[(size_t)(R * BPR + bown) * TN + 0];
        const float* g_ = gtab + (size_t)tok * H3N;
        xr = g_[jown]; xz = g_[HN + jown]; xn = g_[2 * HN + jown];
    }

    // depth-2 poll ring prologue: stages (0,0) and (0,1)
    u64 vcur = 0, vnxt = 0;
    if (tid < 384) {
        vcur = __hip_atomic_load(hb2 + 0 * 384 + tid, __ATOMIC_RELAXED, __HIP_MEMORY_SCOPE_AGENT);
        vnxt = __hip_atomic_load(hb2 + 1 * 384 + tid, __ATOMIC_RELAXED, __HIP_MEMORY_SCOPE_AGENT);
    }

#pragma unroll 1
    for (int t = 0; t < TN; ++t) {
        const u64 want_pair = ((u64)(unsigned)t << 16) | ((u64)(unsigned)t << 48);
#pragma unroll
        for (int b = 0; b < BPR; ++b) {
            // ---- verify (first-try in steady state) + deposit
            if (tid < 384) {
                const u64* cur = hb2 + ((t & 1) * BPR + b) * 384 + tid;
                while ((vcur & 0xFFFF0000FFFF0000ull) != want_pair) {
                    __builtin_amdgcn_s_sleep(1);
                    vcur = __hip_atomic_load(cur, __ATOMIC_RELAXED, __HIP_MEMORY_SCOPE_AGENT);
                }
                *(unsigned*)(dep + b * 896) =
                    __builtin_amdgcn_perm((unsigned)(vcur >> 32), (unsigned)vcur, 0x05040100);
            }
            __syncthreads();                 // tile b complete

            // ---- issue poll for stage s+2 (ring rotate)
            if (tid < 384) {
                int b2 = b + 2;
                const int t2 = t + (b2 >> 2);
                b2 &= 3;
                u64 vnew = 0;
                if (t2 < TN)
                    vnew = __hip_atomic_load(hb2 + ((t2 & 1) * BPR + b2) * 384 + tid,
                                             __ATOMIC_RELAXED, __HIP_MEMORY_SCOPE_AGENT);
                vcur = vnxt;
                vnxt = vnew;
            }

            // ---- dot: 72 fdot2 from VGPR weights, DPP-reduce, sums -> LDS
            {
                float ar = 0.f, az = 0.f, an = 0.f;
                const f16x8* hp = (const f16x8*)(hlds + b * 896 + q * 56);
#pragma unroll
                for (int c = 0; c < 6; ++c) {
                    F16x8 hh; hh.v = hp[c];
#pragma unroll
                    for (int p = 0; p < 4; ++p) {
                        ar = fdot2(w[0][c].p[p], hh.p[p], ar);
                        az = fdot2(w[1][c].p[p], hh.p[p], az);
                        an = fdot2(w[2][c].p[p], hh.p[p], an);
                    }
                }
                ar = hexsum(ar); az = hexsum(az); an = hexsum(an);
                if (q == 0) {
                    s_s[0][b][jl] = ar; s_s[1][b][jl] = az; s_s[2][b][jl] = an;
                }
            }
            __syncthreads();                 // sums ready

            // ---- gate block: only this stage's 48 owner threads
            if ((unsigned)(tid - b * 48) < 48u) {
                const float sr = s_s[0][b][jlown];
                const float sz = s_s[1][b][jlown];
                const float sn = s_s[2][b][jlown];
                const float r  = 1.f / (1.f + __expf(-(xr + sr + bhr)));
                const float z  = 1.f / (1.f + __expf(-(xz + sz + bhz)));
                const float nx = xn + r * (sn + bhn);
                const float n  = 1.f - 2.f / (__expf(2.f * nx) + 1.f);   // tanh
                hprev = (1.f - z) * n + z * hprev;
                unsigned pk = ((unsigned)(t + 1) << 16)
                    | (unsigned)__builtin_bit_cast(unsigned short, (_Float16)hprev);
                const unsigned pk2 = __shfl_down(pk, 1, 64);   // neighbor jlown+1
                if (t < TN - 1) {
                    if (!(jlown & 1))
                        __hip_atomic_store(
                            hb2 + (((t + 1) & 1) * BPR + b) * 384 + wg * 24 + (jlown >> 1),
                            (u64)pk | ((u64)pk2 << 32),
                            __ATOMIC_RELAXED, __HIP_MEMORY_SCOPE_AGENT);
                    // prefetch x-gates for (t+1, bown): 4 stages of slack
                    const int tok = tokens[(size_t)(R * BPR + bown) * TN + (t + 1)];
                    const float* g_ = gtab + (size_t)tok * H3N;
                    xr = g_[jown]; xz = g_[HN + jown]; xn = g_[2 * HN + jown];
                } else {
                    hout[(size_t)(R * BPR + bown) * HN + jown] = hprev;
                }
            }
        }
    }
}

// ---------------- K3: logits + log_softmax
__global__ void k_logits(const float* __restrict__ hfin, const float* __restrict__ wout,
                         const float* __restrict__ bout, float* __restrict__ lp) {
    const int b = blockIdx.x;
    const int o = threadIdx.x / 64;
    const int lane = threadIdx.x % 64;
    const float* hrow = hfin + (size_t)b * HN;
    const float* w = wout + (size_t)o * HN;
    float p = 0.f;
    for (int k = lane; k < HN; k += 64) p += hrow[k] * w[k];
    for (int off = 32; off > 0; off >>= 1) p += __shfl_down(p, off, 64);
    __shared__ float lg[ON];
    if (lane == 0) lg[o] = p + bout[o];
    __syncthreads();
    if (threadIdx.x == 0) {
        float m = fmaxf(lg[0], fmaxf(lg[1], lg[2]));
        float s = __expf(lg[0] - m) + __expf(lg[1] - m) + __expf(lg[2] - m);
        float ls = __logf(s);
        lp[b * ON + 0] = lg[0] - m - ls;
        lp[b * ON + 1] = lg[1] - m - ls;
        lp[b * ON + 2] = lg[2] - m - ls;
    }
}

extern "C" void kernel_launch(void* const* d_in, const int* in_sizes, int n_in,
                              void* d_out, int out_size, void* d_ws, size_t ws_size,
                              hipStream_t stream) {
    const int*   tokens = (const int*)d_in[0];
    // d_in[1] = hidden: reference zeroes it, ignored.
    const float* embed  = (const float*)d_in[2];
    const float* wih    = (const float*)d_in[3];
    const float* whh    = (const float*)d_in[4];
    const float* bih    = (const float*)d_in[5];
    const float* bhh    = (const float*)d_in[6];
    const float* wout   = (const float*)d_in[7];
    const float* bout   = (const float*)d_in[8];

    float* out = (float*)d_out;                  // [B*O logprobs][B*H h_final]
    char* ws = (char*)d_ws;
    const size_t GTAB_OFF = 0;                   // 401*2304*4 = 3,695,616
    const size_t HBUF_OFF = 3695616;             // 16*2*4*384*8 = 393,216 (tagged u64)
    float*    gtab = (float*)(ws + GTAB_OFF);
    unsigned* hbuf = (unsigned*)(ws + HBUF_OFF);

    // tag protocol requires tag==0 / h==0 state on EVERY launch (graph-replayed)
    hipMemsetAsync(ws + HBUF_OFF, 0, 393216, stream);

    hipLaunchKernelGGL(k_build_gtab, dim3(H3N / 64, 16), dim3(256), 0, stream,
                       embed, wih, bih, gtab);
    hipLaunchKernelGGL(k_rnn, dim3(NREP * WGPR), dim3(NTH), 0, stream,
                       tokens, whh, gtab, bhh, hbuf, out + BN * ON);
    hipLaunchKernelGGL(k_logits, dim3(BN), dim3(192), 0, stream,
                       out + BN * ON, wout, bout, out);
}

// Round 12
// 4768.727 us; speedup vs baseline: 1.1581x; 1.1581x over previous
//
#include <hip/hip_runtime.h>

#define VOCABN 401
#define EN 256
#define HN 768
#define H3N 2304
#define ON 3
#define BN 64
#define TN 1024

// 16 replicas x 16 WGs; WG = 768 threads: 48 j's x 16 k-slices; 4 staged batches
#define NREP 16
#define WGPR 16
#define BPR  4
#define JPW  48
#define NTH  768

typedef _Float16 f16x2 __attribute__((ext_vector_type(2)));
typedef _Float16 f16x8 __attribute__((ext_vector_type(8)));
typedef unsigned long long u64;
union F16x8 { f16x8 v; f16x2 p[4]; };

__device__ __forceinline__ float fdot2(f16x2 a, f16x2 b, float c) {
#if __has_builtin(__builtin_amdgcn_fdot2)
    return __builtin_amdgcn_fdot2(a, b, c, false);
#else
    return c + (float)a[0] * (float)b[0] + (float)a[1] * (float)b[1];
#endif
}

// workgroup barrier that drains ONLY lgkm (LDS) — in-flight global (poll) loads
// survive the barrier. This is the whole point of round 12.
__device__ __forceinline__ void barrier_lgkm() {
    asm volatile("s_waitcnt lgkmcnt(0)\n\ts_barrier" ::: "memory");
}

// sum across each aligned 16-lane group; pure-VALU DPP butterfly.
__device__ __forceinline__ float hexsum(float x) {
    int v = __builtin_bit_cast(int, x);
    x += __builtin_bit_cast(float, __builtin_amdgcn_update_dpp(0, v, 0xB1, 0xF, 0xF, true));
    v = __builtin_bit_cast(int, x);
    x += __builtin_bit_cast(float, __builtin_amdgcn_update_dpp(0, v, 0x4E, 0xF, 0xF, true));
    v = __builtin_bit_cast(int, x);
    x += __builtin_bit_cast(float, __builtin_amdgcn_update_dpp(0, v, 0x141, 0xF, 0xF, true));
    v = __builtin_bit_cast(int, x);
    x += __builtin_bit_cast(float, __builtin_amdgcn_update_dpp(0, v, 0x140, 0xF, 0xF, true));
    return x;
}

// ---------------- K1: gtab[v][g] = dot(embed[v], W_ih[g]) + b_ih[g]  (w-stationary)
__global__ __launch_bounds__(256)
void k_build_gtab(const float* __restrict__ embed, const float* __restrict__ wih,
                  const float* __restrict__ bih, float* __restrict__ gtab) {
    const int g  = blockIdx.x * 64 + (threadIdx.x >> 2);
    const int ql = threadIdx.x & 3;
    const int v0 = blockIdx.y * 26;
    const int v1 = min(VOCABN, v0 + 26);
    float4 w[16];
    const float4* s4 = (const float4*)(wih + (size_t)g * EN + ql * 64);
#pragma unroll
    for (int i = 0; i < 16; ++i) w[i] = s4[i];
    const float bias = bih[g];
    for (int v = v0; v < v1; ++v) {
        const float4* e4 = (const float4*)(embed + (size_t)v * EN + ql * 64);
        float acc = 0.f;
#pragma unroll
        for (int i = 0; i < 16; ++i) {
            float4 e = e4[i];
            acc += w[i].x * e.x + w[i].y * e.y + w[i].z * e.z + w[i].w * e.w;
        }
        acc += __shfl_xor(acc, 1, 64);
        acc += __shfl_xor(acc, 2, 64);
        if (ql == 0) gtab[(size_t)v * H3N + g] = acc + bias;
    }
}

// ---------------- K2: persistent-weight recurrence; batch-staggered pipeline,
// depth-2 poll ring, lgkm-only barriers (polls stay in flight across stages).
// h word (u32): [31:16]=step tag, [15:0]=f16 bits; u64 = j-pair. memset-0 == t=0.
// Stage (t,b): verify vcur (first-try in steady state) + v_perm deposit | bar(lgkm)
// | rotate ring (issue load for stage+2) | dot(b) | DPP-reduce | gate on owner
// lanes q==b | paired tagged store. Anti-overwrite induction as r9/r10.
__global__ __launch_bounds__(NTH, 1)
void k_rnn(const int* __restrict__ tokens, const float* __restrict__ whh,
           const float* __restrict__ gtab, const float* __restrict__ bhh,
           unsigned* __restrict__ hbuf, float* __restrict__ hout) {
    const int R   = blockIdx.x & (NREP - 1);
    const int wg  = blockIdx.x >> 4;
    const int tid = threadIdx.x;
    const int jl  = tid >> 4;                  // 0..47
    const int q   = tid & 15;                  // k-slice
    const int j   = wg * JPW + jl;

    __shared__ __align__(16) _Float16 hlds[BPR * 16 * 56];  // [b][q][48+8pad] = 7168 B

    // ---- one-time: weight slice -> 18 statically-indexed f16x8 (72 VGPRs)
    F16x8 w[3][6];
#pragma unroll
    for (int g = 0; g < 3; ++g) {
        const float4* s4 = (const float4*)(whh + (size_t)(g * HN + j) * HN + q * 48);
#pragma unroll
        for (int c = 0; c < 6; ++c) {
            float4 a = s4[2 * c], b4 = s4[2 * c + 1];
            F16x8 t;
            t.v[0] = (_Float16)a.x;  t.v[1] = (_Float16)a.y;
            t.v[2] = (_Float16)a.z;  t.v[3] = (_Float16)a.w;
            t.v[4] = (_Float16)b4.x; t.v[5] = (_Float16)b4.y;
            t.v[6] = (_Float16)b4.z; t.v[7] = (_Float16)b4.w;
            w[g][c] = t;
        }
    }

    const float bhr = bhh[j], bhz = bhh[HN + j], bhn = bhh[2 * HN + j];
    u64* hb2 = (u64*)hbuf + (size_t)R * (2 * BPR * 384);
    // poller deposit ptr: u64 word tid covers global j-pair (2*tid, 2*tid+1)
    unsigned short* dep = (unsigned short*)hlds + (tid / 24) * 56 + (tid % 24) * 2;

    float hprev = 0.f;
    float xr = 0.f, xz = 0.f, xn = 0.f, xrn = 0.f, xzn = 0.f, xnn = 0.f;
    if (q < BPR) {                           // x-gates for t=0 (owner q handles batch q)
        const int tok = tokens[(size_t)(R * BPR + q) * TN + 0];
        const float* g_ = gtab + (size_t)tok * H3N;
        xr = g_[j]; xz = g_[HN + j]; xn = g_[2 * HN + j];
    }

    // depth-2 poll ring prologue: stages (0,0) and (0,1)
    u64 vcur = 0, vnxt = 0;
    if (tid < 384) {
        vcur = __hip_atomic_load(hb2 + 0 * 384 + tid, __ATOMIC_RELAXED, __HIP_MEMORY_SCOPE_AGENT);
        vnxt = __hip_atomic_load(hb2 + 1 * 384 + tid, __ATOMIC_RELAXED, __HIP_MEMORY_SCOPE_AGENT);
    }

#pragma unroll 1
    for (int t = 0; t < TN; ++t) {
        const u64 want_pair = ((u64)(unsigned)t << 16) | ((u64)(unsigned)t << 48);
#pragma unroll
        for (int b = 0; b < BPR; ++b) {
            // ---- verify (first-try in steady state) + deposit (one v_perm pack)
            if (tid < 384) {
                const u64* cur = hb2 + ((t & 1) * BPR + b) * 384 + tid;
                while ((vcur & 0xFFFF0000FFFF0000ull) != want_pair) {
                    __builtin_amdgcn_s_sleep(1);
                    vcur = __hip_atomic_load(cur, __ATOMIC_RELAXED, __HIP_MEMORY_SCOPE_AGENT);
                }
                *(unsigned*)(dep + b * 896) =
                    __builtin_amdgcn_perm((unsigned)(vcur >> 32), (unsigned)vcur, 0x05040100);
            }
            barrier_lgkm();                  // tile b visible; polls stay in flight

            // ---- rotate ring: issue poll load for stage s+2
            if (tid < 384) {
                int b2 = b + 2;
                const int t2 = t + (b2 >> 2);
                b2 &= 3;
                u64 vnew = 0;
                if (t2 < TN)
                    vnew = __hip_atomic_load(hb2 + ((t2 & 1) * BPR + b2) * 384 + tid,
                                             __ATOMIC_RELAXED, __HIP_MEMORY_SCOPE_AGENT);
                vcur = vnxt;
                vnxt = vnew;
            }
            // ---- prefetch next step's x-gates during stage 0 (4 stages of slack)
            if (b == 0 && q < BPR && t < TN - 1) {
                const int tok = tokens[(size_t)(R * BPR + q) * TN + (t + 1)];
                const float* g_ = gtab + (size_t)tok * H3N;
                xrn = g_[j]; xzn = g_[HN + j]; xnn = g_[2 * HN + j];
            }

            // ---- dot: 72 fdot2 from VGPR weights, 16-lane DPP reduce
            float ar = 0.f, az = 0.f, an = 0.f;
            const f16x8* hp = (const f16x8*)(hlds + b * 896 + q * 56);
#pragma unroll
            for (int c = 0; c < 6; ++c) {
                F16x8 hh; hh.v = hp[c];
#pragma unroll
                for (int p = 0; p < 4; ++p) {
                    ar = fdot2(w[0][c].p[p], hh.p[p], ar);
                    az = fdot2(w[1][c].p[p], hh.p[p], az);
                    an = fdot2(w[2][c].p[p], hh.p[p], an);
                }
            }
            const float sr = hexsum(ar), sz = hexsum(az), sn = hexsum(an);

            // ---- gate on owner lanes (q == b), paired tagged store
            unsigned pk = 0;
            if (q == b) {
                const float r  = 1.f / (1.f + __expf(-(xr + sr + bhr)));
                const float z  = 1.f / (1.f + __expf(-(xz + sz + bhz)));
                const float nx = xn + r * (sn + bhn);
                const float n  = 1.f - 2.f / (__expf(2.f * nx) + 1.f);   // tanh
                hprev = (1.f - z) * n + z * hprev;
                pk = ((unsigned)(t + 1) << 16)
                   | (unsigned)__builtin_bit_cast(unsigned short, (_Float16)hprev);
            }
            const unsigned pk2 = __shfl_down(pk, 16, 64);   // pair jl with jl+1
            if (q == b) {
                if (t < TN - 1) {
                    if (!(jl & 1))
                        __hip_atomic_store(
                            hb2 + (((t + 1) & 1) * BPR + b) * 384 + wg * 24 + (jl >> 1),
                            (u64)pk | ((u64)pk2 << 32),
                            __ATOMIC_RELAXED, __HIP_MEMORY_SCOPE_AGENT);
                } else {
                    hout[(size_t)(R * BPR + b) * HN + j] = hprev;
                }
            }
        }
        xr = xrn; xz = xzn; xn = xnn;
    }
}

// ---------------- K3: logits + log_softmax
__global__ void k_logits(const float* __restrict__ hfin, const float* __restrict__ wout,
                         const float* __restrict__ bout, float* __restrict__ lp) {
    const int b = blockIdx.x;
    const int o = threadIdx.x / 64;
    const int lane = threadIdx.x % 64;
    const float* hrow = hfin + (size_t)b * HN;
    const float* w = wout + (size_t)o * HN;
    float p = 0.f;
    for (int k = lane; k < HN; k += 64) p += hrow[k] * w[k];
    for (int off = 32; off > 0; off >>= 1) p += __shfl_down(p, off, 64);
    __shared__ float lg[ON];
    if (lane == 0) lg[o] = p + bout[o];
    __syncthreads();
    if (threadIdx.x == 0) {
        float m = fmaxf(lg[0], fmaxf(lg[1], lg[2]));
        float s = __expf(lg[0] - m) + __expf(lg[1] - m) + __expf(lg[2] - m);
        float ls = __logf(s);
        lp[b * ON + 0] = lg[0] - m - ls;
        lp[b * ON + 1] = lg[1] - m - ls;
        lp[b * ON + 2] = lg[2] - m - ls;
    }
}

extern "C" void kernel_launch(void* const* d_in, const int* in_sizes, int n_in,
                              void* d_out, int out_size, void* d_ws, size_t ws_size,
                              hipStream_t stream) {
    const int*   tokens = (const int*)d_in[0];
    // d_in[1] = hidden: reference zeroes it, ignored.
    const float* embed  = (const float*)d_in[2];
    const float* wih    = (const float*)d_in[3];
    const float* whh    = (const float*)d_in[4];
    const float* bih    = (const float*)d_in[5];
    const float* bhh    = (const float*)d_in[6];
    const float* wout   = (const float*)d_in[7];
    const float* bout   = (const float*)d_in[8];

    float* out = (float*)d_out;                  // [B*O logprobs][B*H h_final]
    char* ws = (char*)d_ws;
    const size_t GTAB_OFF = 0;                   // 401*2304*4 = 3,695,616
    const size_t HBUF_OFF = 3695616;             // 16*2*4*384*8 = 393,216 (tagged u64)
    float*    gtab = (float*)(ws + GTAB_OFF);
    unsigned* hbuf = (unsigned*)(ws + HBUF_OFF);

    // tag protocol requires tag==0 / h==0 state on EVERY launch (graph-replayed)
    hipMemsetAsync(ws + HBUF_OFF, 0, 393216, stream);

    hipLaunchKernelGGL(k_build_gtab, dim3(H3N / 64, 16), dim3(256), 0, stream,
                       embed, wih, bih, gtab);
    hipLaunchKernelGGL(k_rnn, dim3(NREP * WGPR), dim3(NTH), 0, stream,
                       tokens, whh, gtab, bhh, hbuf, out + BN * ON);
    hipLaunchKernelGGL(k_logits, dim3(BN), dim3(192), 0, stream,
                       out + BN * ON, wout, bout, out);
}